// Round 4
// baseline (114.060 us; speedup 1.0000x reference)
//
#include <hip/hip_runtime.h>
#include <hip/hip_bf16.h>
#include <math.h>

#define GAMMA 0.001f
#define HG2   5.0e-7f   // GAMMA^2 / 2
#define Bn 8192
#define Dk 128
#define NGP 512         // G-partial blocks, 16 rows each

typedef float f32x4 __attribute__((ext_vector_type(4)));
typedef short bf16x8 __attribute__((ext_vector_type(8)));

// ---------------- ws layout (bytes) ----------------
// Xb    bf16 [8192][128]    @ 0          (2MB)
// Gp    bf16 [512][16384]   @ 2MB        (16MB)   G partials
// Gb    bf16 [16384]        @ 18MB       (32KB)   G final (symmetric)
// Sp    f32  [512][128]     @ 18MB+32KB  (256KB)  column-sum partials
// S     f32  [128]          @ 18MB+288KB
// em    f32  [8192]         @ 19MB                exp(-Wpos)
// pre   f32  [8192]         @ 19MB+32KB           B + g*x.S - T(Wii) - T(Wpos)
// qpart f32  [2][8192]      @ 19MB+64KB  (64KB)   quad halves (by wn)
// blocksum f32[16]          @ 19MB+128KB ; counter u32 @ +256B
// min1  u32 [65536]         @ 20MB (256KB) ; max1 @ 20MB+256KB

__device__ inline ushort f2b(float x) {
    union { __hip_bfloat16 h; ushort u; } c;
    c.h = __float2bfloat16(x);
    return c.u;
}
__device__ inline float b2f(ushort u) { return __uint_as_float(((unsigned)u) << 16); }

// L1: G-partials (fp32, 8x8 reg tiles) + X->bf16 convert + table init + counter zero
__global__ void k_init(const float* __restrict__ X, ushort* __restrict__ Xb,
                       ushort* __restrict__ Gp, float* __restrict__ Sp,
                       unsigned* __restrict__ min1, unsigned* __restrict__ max1,
                       unsigned* __restrict__ counter) {
    int bid = blockIdx.x, tid = threadIdx.x;
    if (bid < NGP) {
        // G partial over rows [bid*16, bid*16+16)
        __shared__ float xl[16 * 128];
        const float4* src = reinterpret_cast<const float4*>(X) + (size_t)bid * 512;
        float4* dl = reinterpret_cast<float4*>(xl);
        dl[tid] = src[tid];
        dl[tid + 256] = src[tid + 256];
        __syncthreads();
        int tr = (tid >> 4) * 8, tc = (tid & 15) * 8;
        float acc[8][8];
#pragma unroll
        for (int i = 0; i < 8; ++i)
#pragma unroll
            for (int j = 0; j < 8; ++j) acc[i][j] = 0.f;
#pragma unroll
        for (int k = 0; k < 16; ++k) {
            const float* rowk = &xl[k * 128];
            float a[8], b[8];
            *(float4*)&a[0] = *(const float4*)&rowk[tr];
            *(float4*)&a[4] = *(const float4*)&rowk[tr + 4];
            *(float4*)&b[0] = *(const float4*)&rowk[tc];
            *(float4*)&b[4] = *(const float4*)&rowk[tc + 4];
#pragma unroll
            for (int i = 0; i < 8; ++i)
#pragma unroll
                for (int j = 0; j < 8; ++j) acc[i][j] += a[i] * b[j];
        }
        if (tid < 128) {
            float sc = 0.f;
#pragma unroll
            for (int k = 0; k < 16; ++k) sc += xl[k * 128 + tid];
            Sp[bid * 128 + tid] = sc;
        }
        ushort* gpo = Gp + (size_t)bid * 16384 + tr * 128 + tc;
#pragma unroll
        for (int i = 0; i < 8; ++i) {
            ushort4 u0, u1;
            u0.x = f2b(acc[i][0]); u0.y = f2b(acc[i][1]); u0.z = f2b(acc[i][2]); u0.w = f2b(acc[i][3]);
            u1.x = f2b(acc[i][4]); u1.y = f2b(acc[i][5]); u1.z = f2b(acc[i][6]); u1.w = f2b(acc[i][7]);
            *reinterpret_cast<ushort4*>(gpo + i * 128) = u0;
            *reinterpret_cast<ushort4*>(gpo + i * 128 + 4) = u1;
        }
    } else if (bid < NGP + 1024) {
        // fp32 -> bf16 convert, 4 elems/thread
        int i = (bid - NGP) * 256 + tid;
        float4 v = reinterpret_cast<const float4*>(X)[i];
        ushort4 u;
        u.x = f2b(v.x); u.y = f2b(v.y); u.z = f2b(v.z); u.w = f2b(v.w);
        reinterpret_cast<ushort4*>(Xb)[i] = u;
    } else if (bid < NGP + 1024 + 64) {
        int idx = (bid - NGP - 1024) * 256 + tid;   // uint4 index, 0..16383
        uint4 mn = {0xFFFFFFFFu, 0xFFFFFFFFu, 0xFFFFFFFFu, 0xFFFFFFFFu};
        uint4 mx = {0u, 0u, 0u, 0u};
        reinterpret_cast<uint4*>(min1)[idx] = mn;
        reinterpret_cast<uint4*>(max1)[idx] = mx;
    } else {
        if (tid == 0) *counter = 0u;
    }
}

// L2: G reduce (512 partials -> Gb bf16) + label-table fill + S reduce
__global__ void k_mid(const int* __restrict__ tgt, const ushort* __restrict__ Gp,
                      ushort* __restrict__ Gb, const float* __restrict__ Sp,
                      float* __restrict__ S,
                      unsigned* __restrict__ min1, unsigned* __restrict__ max1) {
    int bid = blockIdx.x, tid = threadIdx.x;
    if (bid < 64) {
        int e = bid * 256 + tid;
        float a0 = 0.f, a1 = 0.f, a2 = 0.f, a3 = 0.f;
#pragma unroll 4
        for (int p = 0; p < NGP; p += 4) {
            a0 += b2f(Gp[(size_t)p * 16384 + e]);
            a1 += b2f(Gp[(size_t)(p + 1) * 16384 + e]);
            a2 += b2f(Gp[(size_t)(p + 2) * 16384 + e]);
            a3 += b2f(Gp[(size_t)(p + 3) * 16384 + e]);
        }
        Gb[e] = f2b((a0 + a1) + (a2 + a3));
    } else if (bid < 96) {
        int j = (bid - 64) * 256 + tid;
        unsigned l = (unsigned)tgt[j] & 65535u;
        atomicMin(&min1[l], (unsigned)j);
        atomicMax(&max1[l], (unsigned)j);
    } else {
        if (tid < 128) {
            float sc = 0.f;
            for (int p = 0; p < NGP; ++p) sc += Sp[p * 128 + tid];
            S[tid] = sc;
        }
    }
}

// L3: Z = Xb*Gb MFMA (64 blocks) with fused quad_i = row_i(Z) . x_i epilogue,
//     + per-row prep (128 blocks): em[i], pre[i]
__launch_bounds__(256, 2)
__global__ void k_main(const ushort* __restrict__ Xb, const ushort* __restrict__ Gb,
                       const float* __restrict__ X, const float* __restrict__ S,
                       const int* __restrict__ tgt,
                       const unsigned* __restrict__ min1, const unsigned* __restrict__ max1,
                       float* __restrict__ qpart, float* __restrict__ em,
                       float* __restrict__ pre) {
    int bid = blockIdx.x, tid = threadIdx.x;
    int lane = tid & 63, wid = tid >> 6;
    if (bid < 64) {
        __shared__ ushort sm[32768];   // [0,16384): Xb tile ; [16384,32768): Gb
        const ushort* gA = Xb + (size_t)bid * 16384;
#pragma unroll
        for (int it = 0; it < 8; ++it) {
            int ob = wid * 512 + it * 64;
            int o = ob + lane;
            int src = (o & ~15) | ((o & 15) ^ ((o >> 4) & 7));
            __builtin_amdgcn_global_load_lds(
                (const __attribute__((address_space(1))) void*)(gA + (size_t)src * 8),
                (__attribute__((address_space(3))) void*)(sm + ob * 8), 16, 0, 0);
            __builtin_amdgcn_global_load_lds(
                (const __attribute__((address_space(1))) void*)(Gb + (size_t)src * 8),
                (__attribute__((address_space(3))) void*)(sm + 16384 + ob * 8), 16, 0, 0);
        }
        __syncthreads();
        int wm = wid >> 1, wn = wid & 1, r15 = lane & 15, khalf = lane >> 4;
        const bf16x8* XA = reinterpret_cast<const bf16x8*>(sm);
        const bf16x8* GBL = reinterpret_cast<const bf16x8*>(sm + 16384);
        f32x4 acc[4][4];
#pragma unroll
        for (int m = 0; m < 4; ++m)
#pragma unroll
            for (int n = 0; n < 4; ++n) acc[m][n] = (f32x4){0.f, 0.f, 0.f, 0.f};
#pragma unroll
        for (int ks = 0; ks < 4; ++ks) {
            int u0 = ks * 4 + khalf;
            bf16x8 a[4], b[4];
#pragma unroll
            for (int m = 0; m < 4; ++m) {
                int row = wm * 64 + m * 16 + r15;
                a[m] = XA[row * 16 + (u0 ^ (row & 7))];
            }
#pragma unroll
            for (int n = 0; n < 4; ++n) {
                int row = wn * 64 + n * 16 + r15;
                b[n] = GBL[row * 16 + (u0 ^ (row & 7))];
            }
#pragma unroll
            for (int m = 0; m < 4; ++m)
#pragma unroll
                for (int n = 0; n < 4; ++n)
                    acc[m][n] = __builtin_amdgcn_mfma_f32_16x16x32_bf16(a[m], b[n], acc[m][n], 0, 0, 0);
        }
        // quad epilogue: qp[m][r] = sum_c Z[i][c] * Xb[i][c] over this wave's 64 cols
        float qp[4][4];
#pragma unroll
        for (int m = 0; m < 4; ++m)
#pragma unroll
            for (int r = 0; r < 4; ++r) qp[m][r] = 0.f;
#pragma unroll
        for (int m = 0; m < 4; ++m)
#pragma unroll
            for (int n = 0; n < 4; ++n) {
                int c = wn * 64 + n * 16 + r15;
#pragma unroll
                for (int r = 0; r < 4; ++r) {
                    int il = wm * 64 + m * 16 + khalf * 4 + r;
                    ushort xu = sm[il * 128 + (((c >> 3) ^ (il & 7)) << 3) + (c & 7)];
                    qp[m][r] += acc[m][n][r] * b2f(xu);
                }
            }
#pragma unroll
        for (int m = 0; m < 4; ++m)
#pragma unroll
            for (int r = 0; r < 4; ++r) {
                float v = qp[m][r];
                v += __shfl_xor(v, 1);
                v += __shfl_xor(v, 2);
                v += __shfl_xor(v, 4);
                v += __shfl_xor(v, 8);
                qp[m][r] = v;
            }
        if (r15 == 0) {
#pragma unroll
            for (int m = 0; m < 4; ++m)
#pragma unroll
                for (int r = 0; r < 4; ++r)
                    qpart[(size_t)wn * Bn + bid * 128 + wm * 64 + m * 16 + khalf * 4 + r] = qp[m][r];
        }
    } else {
        // per-row prep: wave per row
        int rb = bid - 64;
        float sv0 = S[lane], sv1 = S[lane + 64];
        for (int it = 0; it < 16; ++it) {
            int i = rb * 64 + wid * 16 + it;
            unsigned ti = (unsigned)tgt[i] & 65535u;
            unsigned m1 = min1[ti], mx = max1[ti];
            int pos = (m1 == (unsigned)i) ? (int)mx : (int)m1;
            if (m1 == 0xFFFFFFFFu || pos == i) pos = 0;   // argmax(all-false)==0
            float x0 = X[(size_t)i * 128 + lane], x1 = X[(size_t)i * 128 + 64 + lane];
            float p0 = X[(size_t)pos * 128 + lane], p1 = X[(size_t)pos * 128 + 64 + lane];
            float dp = x0 * p0 + x1 * p1;
            float ds = x0 * x0 + x1 * x1;
            float sl = x0 * sv0 + x1 * sv1;
            for (int off = 32; off; off >>= 1) {
                dp += __shfl_xor(dp, off);
                ds += __shfl_xor(ds, off);
                sl += __shfl_xor(sl, off);
            }
            if (lane == 0) {
                float wp = GAMMA * dp, wi = GAMMA * ds;
                em[i] = __expf(-wp);
                pre[i] = 8192.0f + GAMMA * sl
                         - (1.0f + wi + 0.5f * wi * wi)
                         - (1.0f + wp + 0.5f * wp * wp);
            }
        }
    }
}

// L4: s_i = em*(pre + HG2*quad); loss = mean(log1p(s)); grid reduce via counter
__global__ void k_fin(const float* __restrict__ qpart, const float* __restrict__ em,
                      const float* __restrict__ pre, float* __restrict__ blocksum,
                      unsigned* __restrict__ counter, float* __restrict__ out) {
    int bid = blockIdx.x, tid = threadIdx.x;
    float v = 0.f;
#pragma unroll
    for (int h = 0; h < 2; ++h) {
        int r = bid * 512 + h * 256 + tid;
        float q = qpart[r] + qpart[Bn + r];
        float s = em[r] * (pre[r] + HG2 * q);
        v += log1pf(s);
    }
    for (int off = 32; off; off >>= 1) v += __shfl_xor(v, off);
    __shared__ float a4[4];
    __shared__ bool last;
    int lane = tid & 63, wid = tid >> 6;
    if (lane == 0) a4[wid] = v;
    __syncthreads();
    if (tid == 0) {
        blocksum[bid] = a4[0] + a4[1] + a4[2] + a4[3];
        __threadfence();
        unsigned old = atomicAdd(counter, 1u);
        last = (old == 15u);
    }
    __syncthreads();
    if (last && tid < 16) {
        __threadfence();
        float x = ((volatile float*)blocksum)[tid];
        x += __shfl_xor(x, 1);
        x += __shfl_xor(x, 2);
        x += __shfl_xor(x, 4);
        x += __shfl_xor(x, 8);
        if (tid == 0) out[0] = x * (1.0f / 8192.0f);
    }
}

extern "C" void kernel_launch(void* const* d_in, const int* in_sizes, int n_in,
                              void* d_out, int out_size, void* d_ws, size_t ws_size,
                              hipStream_t stream) {
    const float* X  = (const float*)d_in[0];
    const int* tgt  = (const int*)d_in[1];
    float* out      = (float*)d_out;
    char* ws        = (char*)d_ws;

    const size_t MB = 1024 * 1024;
    ushort* Xb        = (ushort*)ws;
    ushort* Gp        = (ushort*)(ws + 2 * MB);
    ushort* Gb        = (ushort*)(ws + 18 * MB);
    float* Sp         = (float*)(ws + 18 * MB + 32 * 1024);
    float* S          = (float*)(ws + 18 * MB + 288 * 1024);
    float* em         = (float*)(ws + 19 * MB);
    float* pre        = (float*)(ws + 19 * MB + 32 * 1024);
    float* qpart      = (float*)(ws + 19 * MB + 64 * 1024);
    float* blocksum   = (float*)(ws + 19 * MB + 128 * 1024);
    unsigned* counter = (unsigned*)(ws + 19 * MB + 128 * 1024 + 256);
    unsigned* min1    = (unsigned*)(ws + 20 * MB);
    unsigned* max1    = (unsigned*)(ws + 20 * MB + 256 * 1024);

    k_init<<<NGP + 1024 + 64 + 1, 256, 0, stream>>>(X, Xb, Gp, Sp, min1, max1, counter);
    k_mid<<<97, 256, 0, stream>>>(tgt, Gp, Gb, Sp, S, min1, max1);
    k_main<<<192, 256, 0, stream>>>(Xb, Gb, X, S, tgt, min1, max1, qpart, em, pre);
    k_fin<<<16, 256, 0, stream>>>(qpart, em, pre, blocksum, counter, out);
}

// Round 5
// 45.400 us; speedup vs baseline: 2.5124x; 2.5124x over previous
//
#include <hip/hip_runtime.h>
#include <hip/hip_bf16.h>
#include <math.h>

#define GAMMA 0.001f
#define HG2   5.0e-7f   // GAMMA^2 / 2
#define Bn 8192
#define Dk 128
#define NGP 128         // G-partial blocks, 64 rows each

typedef float f32x4 __attribute__((ext_vector_type(4)));
typedef short bf16x8 __attribute__((ext_vector_type(8)));

// ---------------- ws layout (bytes) ----------------
// Xb    bf16 [8192][128]    @ 0           (2MB)
// Gpf   f32  [128][16384]   @ 2MB         (8MB)   G partials (f32)
// Gb    bf16 [16384]        @ 10MB        (32KB)  G final (symmetric)
// Sp    f32  [128][128]     @ 10MB+32KB   (64KB)  column-sum partials
// S     f32  [128]          @ 10MB+96KB
// em    f32  [8192]         @ 11MB                exp(-Wpos)
// pre   f32  [8192]         @ 11MB+32KB           B + g*x.S - T(Wii) - T(Wpos)
// qpart f32  [2][8192]      @ 11MB+64KB   (64KB)  quad halves (by wn)
// blocksum f32[16]          @ 11MB+128KB ; counter u32 @ +256B
// min1  u32 [65536]         @ 12MB (256KB) ; max1 @ 12MB+256KB

__device__ inline ushort f2b(float x) {
    union { __hip_bfloat16 h; ushort u; } c;
    c.h = __float2bfloat16(x);
    return c.u;
}
__device__ inline float b2f(ushort u) { return __uint_as_float(((unsigned)u) << 16); }

// L1: G-partials over 64-row slices (4x8 reg tile, f32) + fused X->bf16 convert
//     + label-table init + counter zero
__launch_bounds__(512)
__global__ void k_gpart(const float* __restrict__ X, ushort* __restrict__ Xb,
                        float* __restrict__ Gpf, float* __restrict__ Sp,
                        unsigned* __restrict__ min1, unsigned* __restrict__ max1,
                        unsigned* __restrict__ counter) {
    int bid = blockIdx.x, tid = threadIdx.x;
    if (bid < NGP) {
        __shared__ float xl[64 * 128];   // 32 KB
        const float4* src = reinterpret_cast<const float4*>(X) + (size_t)bid * 2048;
        float4* dl = reinterpret_cast<float4*>(xl);
        ushort4* xbo = reinterpret_cast<ushort4*>(Xb) + (size_t)bid * 2048;
#pragma unroll
        for (int it = 0; it < 4; ++it) {
            int idx = tid + it * 512;
            float4 v = src[idx];
            dl[idx] = v;
            ushort4 u;
            u.x = f2b(v.x); u.y = f2b(v.y); u.z = f2b(v.z); u.w = f2b(v.w);
            xbo[idx] = u;   // fused convert
        }
        __syncthreads();
        int tr = (tid >> 4) * 4, tc = (tid & 15) * 8;
        float acc[4][8];
#pragma unroll
        for (int i = 0; i < 4; ++i)
#pragma unroll
            for (int j = 0; j < 8; ++j) acc[i][j] = 0.f;
        for (int k = 0; k < 64; ++k) {
            const float* rowk = &xl[k * 128];
            float a[4], b[8];
            *(float4*)&a[0] = *(const float4*)&rowk[tr];
            *(float4*)&b[0] = *(const float4*)&rowk[tc];
            *(float4*)&b[4] = *(const float4*)&rowk[tc + 4];
#pragma unroll
            for (int i = 0; i < 4; ++i)
#pragma unroll
                for (int j = 0; j < 8; ++j) acc[i][j] += a[i] * b[j];
        }
        float* go = Gpf + (size_t)bid * 16384 + tr * 128 + tc;
#pragma unroll
        for (int i = 0; i < 4; ++i) {
            *reinterpret_cast<float4*>(go + i * 128)     = (float4){acc[i][0], acc[i][1], acc[i][2], acc[i][3]};
            *reinterpret_cast<float4*>(go + i * 128 + 4) = (float4){acc[i][4], acc[i][5], acc[i][6], acc[i][7]};
        }
        if (tid < 128) {
            float sc = 0.f;
#pragma unroll
            for (int k = 0; k < 64; ++k) sc += xl[k * 128 + tid];
            Sp[bid * 128 + tid] = sc;
        }
    } else if (bid < NGP + 32) {
        int idx = (bid - NGP) * 512 + tid;   // uint4 index 0..16383
        uint4 mn = {0xFFFFFFFFu, 0xFFFFFFFFu, 0xFFFFFFFFu, 0xFFFFFFFFu};
        uint4 mx = {0u, 0u, 0u, 0u};
        reinterpret_cast<uint4*>(min1)[idx] = mn;
        reinterpret_cast<uint4*>(max1)[idx] = mx;
    } else {
        if (tid == 0) *counter = 0u;
    }
}

// L2: G reduce (128 f32 partials -> Gb bf16) + label-table fill + S reduce
__global__ void k_mid(const int* __restrict__ tgt, const float* __restrict__ Gpf,
                      ushort* __restrict__ Gb, const float* __restrict__ Sp,
                      float* __restrict__ S,
                      unsigned* __restrict__ min1, unsigned* __restrict__ max1) {
    int bid = blockIdx.x, tid = threadIdx.x;
    if (bid < 64) {
        int e = bid * 256 + tid;
        float a0 = 0.f, a1 = 0.f, a2 = 0.f, a3 = 0.f;
#pragma unroll 2
        for (int p = 0; p < NGP; p += 4) {
            a0 += Gpf[(size_t)p * 16384 + e];
            a1 += Gpf[(size_t)(p + 1) * 16384 + e];
            a2 += Gpf[(size_t)(p + 2) * 16384 + e];
            a3 += Gpf[(size_t)(p + 3) * 16384 + e];
        }
        Gb[e] = f2b((a0 + a1) + (a2 + a3));
    } else if (bid < 96) {
        int j = (bid - 64) * 256 + tid;
        unsigned l = (unsigned)tgt[j] & 65535u;
        atomicMin(&min1[l], (unsigned)j);
        atomicMax(&max1[l], (unsigned)j);
    } else {
        if (tid < 128) {
            float sc = 0.f;
            for (int p = 0; p < NGP; ++p) sc += Sp[p * 128 + tid];
            S[tid] = sc;
        }
    }
}

// L3: Z = Xb*Gb MFMA (64 blocks) with fused quad_i = row_i(Z) . x_i epilogue,
//     + per-row prep (128 blocks): em[i], pre[i]   [verified in R4]
__launch_bounds__(256, 2)
__global__ void k_main(const ushort* __restrict__ Xb, const ushort* __restrict__ Gb,
                       const float* __restrict__ X, const float* __restrict__ S,
                       const int* __restrict__ tgt,
                       const unsigned* __restrict__ min1, const unsigned* __restrict__ max1,
                       float* __restrict__ qpart, float* __restrict__ em,
                       float* __restrict__ pre) {
    int bid = blockIdx.x, tid = threadIdx.x;
    int lane = tid & 63, wid = tid >> 6;
    if (bid < 64) {
        __shared__ ushort sm[32768];   // [0,16384): Xb tile ; [16384,32768): Gb
        const ushort* gA = Xb + (size_t)bid * 16384;
#pragma unroll
        for (int it = 0; it < 8; ++it) {
            int ob = wid * 512 + it * 64;
            int o = ob + lane;
            int src = (o & ~15) | ((o & 15) ^ ((o >> 4) & 7));
            __builtin_amdgcn_global_load_lds(
                (const __attribute__((address_space(1))) void*)(gA + (size_t)src * 8),
                (__attribute__((address_space(3))) void*)(sm + ob * 8), 16, 0, 0);
            __builtin_amdgcn_global_load_lds(
                (const __attribute__((address_space(1))) void*)(Gb + (size_t)src * 8),
                (__attribute__((address_space(3))) void*)(sm + 16384 + ob * 8), 16, 0, 0);
        }
        __syncthreads();
        int wm = wid >> 1, wn = wid & 1, r15 = lane & 15, khalf = lane >> 4;
        const bf16x8* XA = reinterpret_cast<const bf16x8*>(sm);
        const bf16x8* GBL = reinterpret_cast<const bf16x8*>(sm + 16384);
        f32x4 acc[4][4];
#pragma unroll
        for (int m = 0; m < 4; ++m)
#pragma unroll
            for (int n = 0; n < 4; ++n) acc[m][n] = (f32x4){0.f, 0.f, 0.f, 0.f};
#pragma unroll
        for (int ks = 0; ks < 4; ++ks) {
            int u0 = ks * 4 + khalf;
            bf16x8 a[4], b[4];
#pragma unroll
            for (int m = 0; m < 4; ++m) {
                int row = wm * 64 + m * 16 + r15;
                a[m] = XA[row * 16 + (u0 ^ (row & 7))];
            }
#pragma unroll
            for (int n = 0; n < 4; ++n) {
                int row = wn * 64 + n * 16 + r15;
                b[n] = GBL[row * 16 + (u0 ^ (row & 7))];
            }
#pragma unroll
            for (int m = 0; m < 4; ++m)
#pragma unroll
                for (int n = 0; n < 4; ++n)
                    acc[m][n] = __builtin_amdgcn_mfma_f32_16x16x32_bf16(a[m], b[n], acc[m][n], 0, 0, 0);
        }
        // quad epilogue: qp[m][r] = sum_c Z[i][c] * Xb[i][c] over this wave's 64 cols
        float qp[4][4];
#pragma unroll
        for (int m = 0; m < 4; ++m)
#pragma unroll
            for (int r = 0; r < 4; ++r) qp[m][r] = 0.f;
#pragma unroll
        for (int m = 0; m < 4; ++m)
#pragma unroll
            for (int n = 0; n < 4; ++n) {
                int c = wn * 64 + n * 16 + r15;
#pragma unroll
                for (int r = 0; r < 4; ++r) {
                    int il = wm * 64 + m * 16 + khalf * 4 + r;
                    ushort xu = sm[il * 128 + (((c >> 3) ^ (il & 7)) << 3) + (c & 7)];
                    qp[m][r] += acc[m][n][r] * b2f(xu);
                }
            }
#pragma unroll
        for (int m = 0; m < 4; ++m)
#pragma unroll
            for (int r = 0; r < 4; ++r) {
                float v = qp[m][r];
                v += __shfl_xor(v, 1);
                v += __shfl_xor(v, 2);
                v += __shfl_xor(v, 4);
                v += __shfl_xor(v, 8);
                qp[m][r] = v;
            }
        if (r15 == 0) {
#pragma unroll
            for (int m = 0; m < 4; ++m)
#pragma unroll
                for (int r = 0; r < 4; ++r)
                    qpart[(size_t)wn * Bn + bid * 128 + wm * 64 + m * 16 + khalf * 4 + r] = qp[m][r];
        }
    } else {
        // per-row prep: wave per row
        int rb = bid - 64;
        float sv0 = S[lane], sv1 = S[lane + 64];
        for (int it = 0; it < 16; ++it) {
            int i = rb * 64 + wid * 16 + it;
            unsigned ti = (unsigned)tgt[i] & 65535u;
            unsigned m1 = min1[ti], mx = max1[ti];
            int pos = (m1 == (unsigned)i) ? (int)mx : (int)m1;
            if (m1 == 0xFFFFFFFFu || pos == i) pos = 0;   // argmax(all-false)==0
            float x0 = X[(size_t)i * 128 + lane], x1 = X[(size_t)i * 128 + 64 + lane];
            float p0 = X[(size_t)pos * 128 + lane], p1 = X[(size_t)pos * 128 + 64 + lane];
            float dp = x0 * p0 + x1 * p1;
            float ds = x0 * x0 + x1 * x1;
            float sl = x0 * sv0 + x1 * sv1;
            for (int off = 32; off; off >>= 1) {
                dp += __shfl_xor(dp, off);
                ds += __shfl_xor(ds, off);
                sl += __shfl_xor(sl, off);
            }
            if (lane == 0) {
                float wp = GAMMA * dp, wi = GAMMA * ds;
                em[i] = __expf(-wp);
                pre[i] = 8192.0f + GAMMA * sl
                         - (1.0f + wi + 0.5f * wi * wi)
                         - (1.0f + wp + 0.5f * wp * wp);
            }
        }
    }
}

// L4: s_i = em*(pre + HG2*quad); loss = mean(log1p(s)); grid reduce via counter
__global__ void k_fin(const float* __restrict__ qpart, const float* __restrict__ em,
                      const float* __restrict__ pre, float* __restrict__ blocksum,
                      unsigned* __restrict__ counter, float* __restrict__ out) {
    int bid = blockIdx.x, tid = threadIdx.x;
    float v = 0.f;
#pragma unroll
    for (int h = 0; h < 2; ++h) {
        int r = bid * 512 + h * 256 + tid;
        float q = qpart[r] + qpart[Bn + r];
        float s = em[r] * (pre[r] + HG2 * q);
        v += log1pf(s);
    }
    for (int off = 32; off; off >>= 1) v += __shfl_xor(v, off);
    __shared__ float a4[4];
    __shared__ bool last;
    int lane = tid & 63, wid = tid >> 6;
    if (lane == 0) a4[wid] = v;
    __syncthreads();
    if (tid == 0) {
        blocksum[bid] = a4[0] + a4[1] + a4[2] + a4[3];
        __threadfence();
        unsigned old = atomicAdd(counter, 1u);
        last = (old == 15u);
    }
    __syncthreads();
    if (last && tid < 16) {
        __threadfence();
        float x = ((volatile float*)blocksum)[tid];
        x += __shfl_xor(x, 1);
        x += __shfl_xor(x, 2);
        x += __shfl_xor(x, 4);
        x += __shfl_xor(x, 8);
        if (tid == 0) out[0] = x * (1.0f / 8192.0f);
    }
}

extern "C" void kernel_launch(void* const* d_in, const int* in_sizes, int n_in,
                              void* d_out, int out_size, void* d_ws, size_t ws_size,
                              hipStream_t stream) {
    const float* X  = (const float*)d_in[0];
    const int* tgt  = (const int*)d_in[1];
    float* out      = (float*)d_out;
    char* ws        = (char*)d_ws;

    const size_t MB = 1024 * 1024;
    ushort* Xb        = (ushort*)ws;
    float* Gpf        = (float*)(ws + 2 * MB);
    ushort* Gb        = (ushort*)(ws + 10 * MB);
    float* Sp         = (float*)(ws + 10 * MB + 32 * 1024);
    float* S          = (float*)(ws + 10 * MB + 96 * 1024);
    float* em         = (float*)(ws + 11 * MB);
    float* pre        = (float*)(ws + 11 * MB + 32 * 1024);
    float* qpart      = (float*)(ws + 11 * MB + 64 * 1024);
    float* blocksum   = (float*)(ws + 11 * MB + 128 * 1024);
    unsigned* counter = (unsigned*)(ws + 11 * MB + 128 * 1024 + 256);
    unsigned* min1    = (unsigned*)(ws + 12 * MB);
    unsigned* max1    = (unsigned*)(ws + 12 * MB + 256 * 1024);

    k_gpart<<<NGP + 32 + 1, 512, 0, stream>>>(X, Xb, Gpf, Sp, min1, max1, counter);
    k_mid<<<97, 256, 0, stream>>>(tgt, Gpf, Gb, Sp, S, min1, max1);
    k_main<<<192, 256, 0, stream>>>(Xb, Gb, X, S, tgt, min1, max1, qpart, em, pre);
    k_fin<<<16, 256, 0, stream>>>(qpart, em, pre, blocksum, counter, out);
}

// Round 6
// 36.100 us; speedup vs baseline: 3.1596x; 1.2576x over previous
//
#include <hip/hip_runtime.h>
#include <hip/hip_bf16.h>
#include <math.h>

#define GAMMA 0.001f
#define HG2   5.0e-7f   // GAMMA^2 / 2
#define Bn 8192
#define Dk 128
#define NGP 256         // G-partial blocks, 32 rows each

typedef float f32x4 __attribute__((ext_vector_type(4)));
typedef short bf16x8 __attribute__((ext_vector_type(8)));

// ---------------- ws layout (bytes) ----------------
// Xb    bf16 [8192][128]    @ 0           (2MB)
// Gpb   bf16 [256][16384]   @ 2MB         (8MB)   G partials (bf16)
// Gb    bf16 [16384]        @ 10MB        (32KB)  G final (symmetric)
// Sp    f32  [256][128]     @ 10MB+32KB   (128KB) column-sum partials
// S     f32  [128]          @ 10MB+192KB
// em    f32  [8192]         @ 11MB                exp(-Wpos)
// pre   f32  [8192]         @ 11MB+32KB
// qpart f32  [2][8192]      @ 11MB+64KB   (64KB)
// blocksum f32[16]          @ 11MB+128KB ; counter u32 @ +256B
// min1  u32 [65536]         @ 12MB (256KB) ; max1 @ 12MB+256KB

__device__ inline ushort f2b(float x) {
    union { __hip_bfloat16 h; ushort u; } c;
    c.h = __float2bfloat16(x);
    return c.u;
}
__device__ inline float b2f(ushort u) { return __uint_as_float(((unsigned)u) << 16); }

// L1: G-partials over 32-row slices (4x8 reg tile, f32 acc -> bf16 out)
//     + fused X->bf16 convert + label-table init + counter zero
__launch_bounds__(512)
__global__ void k_gpart(const float* __restrict__ X, ushort* __restrict__ Xb,
                        ushort* __restrict__ Gpb, float* __restrict__ Sp,
                        unsigned* __restrict__ min1, unsigned* __restrict__ max1,
                        unsigned* __restrict__ counter) {
    int bid = blockIdx.x, tid = threadIdx.x;
    __shared__ float xl[32 * 128];   // 16 KB
    const float4* src = reinterpret_cast<const float4*>(X) + (size_t)bid * 1024;
    float4* dl = reinterpret_cast<float4*>(xl);
    ushort4* xbo = reinterpret_cast<ushort4*>(Xb) + (size_t)bid * 1024;
#pragma unroll
    for (int it = 0; it < 2; ++it) {
        int idx = tid + it * 512;
        float4 v = src[idx];
        dl[idx] = v;
        ushort4 u;
        u.x = f2b(v.x); u.y = f2b(v.y); u.z = f2b(v.z); u.w = f2b(v.w);
        xbo[idx] = u;   // fused convert
    }
    if (bid < 128) {   // label-table init: 128 blocks x 512 = 65536 entries
        min1[bid * 512 + tid] = 0xFFFFFFFFu;
        max1[bid * 512 + tid] = 0u;
    }
    if (bid == 0 && tid == 0) *counter = 0u;
    __syncthreads();

    int tr = (tid >> 4) * 4, tc = (tid & 15) * 8;
    float acc[4][8];
#pragma unroll
    for (int i = 0; i < 4; ++i)
#pragma unroll
        for (int j = 0; j < 8; ++j) acc[i][j] = 0.f;
#pragma unroll 4
    for (int k = 0; k < 32; ++k) {
        const float* rowk = &xl[k * 128];
        float a[4], b[8];
        *(float4*)&a[0] = *(const float4*)&rowk[tr];
        *(float4*)&b[0] = *(const float4*)&rowk[tc];
        *(float4*)&b[4] = *(const float4*)&rowk[tc + 4];
#pragma unroll
        for (int i = 0; i < 4; ++i)
#pragma unroll
            for (int j = 0; j < 8; ++j) acc[i][j] += a[i] * b[j];
    }
    ushort* gpo = Gpb + (size_t)bid * 16384 + tr * 128 + tc;
#pragma unroll
    for (int i = 0; i < 4; ++i) {
        union { ushort s[8]; uint4 v; } pk;
#pragma unroll
        for (int j = 0; j < 8; ++j) pk.s[j] = f2b(acc[i][j]);
        *reinterpret_cast<uint4*>(gpo + i * 128) = pk.v;
    }
    if (tid < 128) {
        float sc = 0.f;
#pragma unroll
        for (int k = 0; k < 32; ++k) sc += xl[k * 128 + tid];
        Sp[bid * 128 + tid] = sc;
    }
}

// L2: G reduce (256 bf16 partials -> Gb bf16; coalesced pc-split) + tab fill + S reduce
__global__ void k_mid(const int* __restrict__ tgt, const ushort* __restrict__ Gpb,
                      ushort* __restrict__ Gb, const float* __restrict__ Sp,
                      float* __restrict__ S,
                      unsigned* __restrict__ min1, unsigned* __restrict__ max1) {
    int bid = blockIdx.x, tid = threadIdx.x;
    if (bid < 64) {
        // block b: eg in [b*32, b*32+32) (8 G-elems each); pc = tid>>5 covers 32 partials
        int el = tid & 31, pc = tid >> 5;
        int eg = bid * 32 + el;
        float a8[8];
#pragma unroll
        for (int j = 0; j < 8; ++j) a8[j] = 0.f;
        const ushort* base = Gpb + (size_t)eg * 8;
#pragma unroll 4
        for (int k = 0; k < 32; ++k) {
            int p = pc + k * 8;
            union { uint4 v; ushort s[8]; } ld;
            ld.v = *reinterpret_cast<const uint4*>(base + (size_t)p * 16384);
#pragma unroll
            for (int j = 0; j < 8; ++j) a8[j] += b2f(ld.s[j]);
        }
        __shared__ float red[8][32][8];
#pragma unroll
        for (int j = 0; j < 8; ++j) red[pc][el][j] = a8[j];
        __syncthreads();
        if (tid < 32) {
            union { ushort s[8]; uint4 v; } pk;
#pragma unroll
            for (int j = 0; j < 8; ++j) {
                float v = 0.f;
#pragma unroll
                for (int p = 0; p < 8; ++p) v += red[p][tid][j];
                pk.s[j] = f2b(v);
            }
            *reinterpret_cast<uint4*>(Gb + (size_t)eg * 8) = pk.v;
        }
    } else if (bid < 96) {
        int j = (bid - 64) * 256 + tid;
        unsigned l = (unsigned)tgt[j] & 65535u;
        atomicMin(&min1[l], (unsigned)j);
        atomicMax(&max1[l], (unsigned)j);
    } else {
        if (tid < 128) {
            float sc = 0.f;
            for (int p = 0; p < NGP; ++p) sc += Sp[p * 128 + tid];
            S[tid] = sc;
        }
    }
}

// L3: Z = Xb*Gb MFMA (64 blocks) with fused quad epilogue + per-row prep (128 blocks)
__launch_bounds__(256, 2)
__global__ void k_main(const ushort* __restrict__ Xb, const ushort* __restrict__ Gb,
                       const float* __restrict__ X, const float* __restrict__ S,
                       const int* __restrict__ tgt,
                       const unsigned* __restrict__ min1, const unsigned* __restrict__ max1,
                       float* __restrict__ qpart, float* __restrict__ em,
                       float* __restrict__ pre) {
    int bid = blockIdx.x, tid = threadIdx.x;
    int lane = tid & 63, wid = tid >> 6;
    if (bid < 64) {
        __shared__ ushort sm[32768];   // [0,16384): Xb tile ; [16384,32768): Gb
        const ushort* gA = Xb + (size_t)bid * 16384;
#pragma unroll
        for (int it = 0; it < 8; ++it) {
            int ob = wid * 512 + it * 64;
            int o = ob + lane;
            int src = (o & ~15) | ((o & 15) ^ ((o >> 4) & 7));
            __builtin_amdgcn_global_load_lds(
                (const __attribute__((address_space(1))) void*)(gA + (size_t)src * 8),
                (__attribute__((address_space(3))) void*)(sm + ob * 8), 16, 0, 0);
            __builtin_amdgcn_global_load_lds(
                (const __attribute__((address_space(1))) void*)(Gb + (size_t)src * 8),
                (__attribute__((address_space(3))) void*)(sm + 16384 + ob * 8), 16, 0, 0);
        }
        __syncthreads();
        int wm = wid >> 1, wn = wid & 1, r15 = lane & 15, khalf = lane >> 4;
        const bf16x8* XA = reinterpret_cast<const bf16x8*>(sm);
        const bf16x8* GBL = reinterpret_cast<const bf16x8*>(sm + 16384);
        f32x4 acc[4][4];
#pragma unroll
        for (int m = 0; m < 4; ++m)
#pragma unroll
            for (int n = 0; n < 4; ++n) acc[m][n] = (f32x4){0.f, 0.f, 0.f, 0.f};
#pragma unroll
        for (int ks = 0; ks < 4; ++ks) {
            int u0 = ks * 4 + khalf;
            bf16x8 a[4], b[4];
#pragma unroll
            for (int m = 0; m < 4; ++m) {
                int row = wm * 64 + m * 16 + r15;
                a[m] = XA[row * 16 + (u0 ^ (row & 7))];
            }
#pragma unroll
            for (int n = 0; n < 4; ++n) {
                int row = wn * 64 + n * 16 + r15;
                b[n] = GBL[row * 16 + (u0 ^ (row & 7))];
            }
#pragma unroll
            for (int m = 0; m < 4; ++m)
#pragma unroll
                for (int n = 0; n < 4; ++n)
                    acc[m][n] = __builtin_amdgcn_mfma_f32_16x16x32_bf16(a[m], b[n], acc[m][n], 0, 0, 0);
        }
        float qp[4][4];
#pragma unroll
        for (int m = 0; m < 4; ++m)
#pragma unroll
            for (int r = 0; r < 4; ++r) qp[m][r] = 0.f;
#pragma unroll
        for (int m = 0; m < 4; ++m)
#pragma unroll
            for (int n = 0; n < 4; ++n) {
                int c = wn * 64 + n * 16 + r15;
#pragma unroll
                for (int r = 0; r < 4; ++r) {
                    int il = wm * 64 + m * 16 + khalf * 4 + r;
                    ushort xu = sm[il * 128 + (((c >> 3) ^ (il & 7)) << 3) + (c & 7)];
                    qp[m][r] += acc[m][n][r] * b2f(xu);
                }
            }
#pragma unroll
        for (int m = 0; m < 4; ++m)
#pragma unroll
            for (int r = 0; r < 4; ++r) {
                float v = qp[m][r];
                v += __shfl_xor(v, 1);
                v += __shfl_xor(v, 2);
                v += __shfl_xor(v, 4);
                v += __shfl_xor(v, 8);
                qp[m][r] = v;
            }
        if (r15 == 0) {
#pragma unroll
            for (int m = 0; m < 4; ++m)
#pragma unroll
                for (int r = 0; r < 4; ++r)
                    qpart[(size_t)wn * Bn + bid * 128 + wm * 64 + m * 16 + khalf * 4 + r] = qp[m][r];
        }
    } else {
        int rb = bid - 64;
        float sv0 = S[lane], sv1 = S[lane + 64];
        for (int it = 0; it < 16; ++it) {
            int i = rb * 64 + wid * 16 + it;
            unsigned ti = (unsigned)tgt[i] & 65535u;
            unsigned m1 = min1[ti], mx = max1[ti];
            int pos = (m1 == (unsigned)i) ? (int)mx : (int)m1;
            if (m1 == 0xFFFFFFFFu || pos == i) pos = 0;   // argmax(all-false)==0
            float x0 = X[(size_t)i * 128 + lane], x1 = X[(size_t)i * 128 + 64 + lane];
            float p0 = X[(size_t)pos * 128 + lane], p1 = X[(size_t)pos * 128 + 64 + lane];
            float dp = x0 * p0 + x1 * p1;
            float ds = x0 * x0 + x1 * x1;
            float sl = x0 * sv0 + x1 * sv1;
            for (int off = 32; off; off >>= 1) {
                dp += __shfl_xor(dp, off);
                ds += __shfl_xor(ds, off);
                sl += __shfl_xor(sl, off);
            }
            if (lane == 0) {
                float wp = GAMMA * dp, wi = GAMMA * ds;
                em[i] = __expf(-wp);
                pre[i] = 8192.0f + GAMMA * sl
                         - (1.0f + wi + 0.5f * wi * wi)
                         - (1.0f + wp + 0.5f * wp * wp);
            }
        }
    }
}

// L4: s_i = em*(pre + HG2*quad); loss = mean(log1p(s)); grid reduce via counter
__global__ void k_fin(const float* __restrict__ qpart, const float* __restrict__ em,
                      const float* __restrict__ pre, float* __restrict__ blocksum,
                      unsigned* __restrict__ counter, float* __restrict__ out) {
    int bid = blockIdx.x, tid = threadIdx.x;
    float v = 0.f;
#pragma unroll
    for (int h = 0; h < 2; ++h) {
        int r = bid * 512 + h * 256 + tid;
        float q = qpart[r] + qpart[Bn + r];
        float s = em[r] * (pre[r] + HG2 * q);
        v += log1pf(s);
    }
    for (int off = 32; off; off >>= 1) v += __shfl_xor(v, off);
    __shared__ float a4[4];
    __shared__ bool last;
    int lane = tid & 63, wid = tid >> 6;
    if (lane == 0) a4[wid] = v;
    __syncthreads();
    if (tid == 0) {
        blocksum[bid] = a4[0] + a4[1] + a4[2] + a4[3];
        __threadfence();
        unsigned old = atomicAdd(counter, 1u);
        last = (old == 15u);
    }
    __syncthreads();
    if (last && tid < 16) {
        __threadfence();
        float x = ((volatile float*)blocksum)[tid];
        x += __shfl_xor(x, 1);
        x += __shfl_xor(x, 2);
        x += __shfl_xor(x, 4);
        x += __shfl_xor(x, 8);
        if (tid == 0) out[0] = x * (1.0f / 8192.0f);
    }
}

extern "C" void kernel_launch(void* const* d_in, const int* in_sizes, int n_in,
                              void* d_out, int out_size, void* d_ws, size_t ws_size,
                              hipStream_t stream) {
    const float* X  = (const float*)d_in[0];
    const int* tgt  = (const int*)d_in[1];
    float* out      = (float*)d_out;
    char* ws        = (char*)d_ws;

    const size_t MB = 1024 * 1024;
    ushort* Xb        = (ushort*)ws;
    ushort* Gpb       = (ushort*)(ws + 2 * MB);
    ushort* Gb        = (ushort*)(ws + 10 * MB);
    float* Sp         = (float*)(ws + 10 * MB + 32 * 1024);
    float* S          = (float*)(ws + 10 * MB + 192 * 1024);
    float* em         = (float*)(ws + 11 * MB);
    float* pre        = (float*)(ws + 11 * MB + 32 * 1024);
    float* qpart      = (float*)(ws + 11 * MB + 64 * 1024);
    float* blocksum   = (float*)(ws + 11 * MB + 128 * 1024);
    unsigned* counter = (unsigned*)(ws + 11 * MB + 128 * 1024 + 256);
    unsigned* min1    = (unsigned*)(ws + 12 * MB);
    unsigned* max1    = (unsigned*)(ws + 12 * MB + 256 * 1024);

    k_gpart<<<NGP, 512, 0, stream>>>(X, Xb, Gpb, Sp, min1, max1, counter);
    k_mid<<<97, 256, 0, stream>>>(tgt, Gpb, Gb, Sp, S, min1, max1);
    k_main<<<192, 256, 0, stream>>>(Xb, Gb, X, S, tgt, min1, max1, qpart, em, pre);
    k_fin<<<16, 256, 0, stream>>>(qpart, em, pre, blocksum, counter, out);
}